// Round 9
// baseline (1447.767 us; speedup 1.0000x reference)
//
#include <hip/hip_runtime.h>
#include <stdint.h>

#define T_LEN 512
#define IN0   9
#define H     56
#define BG    16               // 16 batch/block: two independent 8-batch groups
#define NW    14
#define NTH   (NW * 64)        // 896 threads; waves 0-6 = group A, 7-13 = group B
#define NBLK  (2048 / BG)      // 128 blocks (idle CUs are free; wall = block chain)

typedef __attribute__((ext_vector_type(8))) short bfrag;   // 8 bf16
typedef __attribute__((ext_vector_type(4))) float ffrag;   // 4 fp32

#define MFMA(a,b,c) __builtin_amdgcn_mfma_f32_16x16x32_bf16((a),(b),(c),0,0,0)

__device__ __forceinline__ uint32_t bf16hi(float x) {
  uint32_t u = __float_as_uint(x);
  return (u + 0x7FFFu + ((u >> 16) & 1u)) & 0xFFFF0000u;
}
__device__ __forceinline__ void split_bf16(float x, short& hs, short& ls) {
  uint32_t hb = bf16hi(x);
  float lf = x - __uint_as_float(hb);
  hs = (short)(hb >> 16);
  ls = (short)(bf16hi(lf) >> 16);
}
__device__ __forceinline__ void split_bf16t(float x, short& hs, short& ls) {
  uint32_t hb = bf16hi(x);
  float lf = x - __uint_as_float(hb);
  hs = (short)(hb >> 16);
  ls = (short)(__float_as_uint(lf) >> 16);
}
__device__ __forceinline__ float dpp8(float v) {
  return __int_as_float(__builtin_amdgcn_update_dpp(0, __float_as_int(v), 0x128, 0xF, 0xF, true));
}
__device__ __forceinline__ float rcp_f(float v)  { return __builtin_amdgcn_rcpf(v); }
__device__ __forceinline__ float sigm_f(float v) { return rcp_f(1.0f + __expf(-v)); }
__device__ __forceinline__ float tanh_f(float v) { return 1.0f - 2.0f * rcp_f(1.0f + __expf(2.0f * v)); }

__global__ __launch_bounds__(NTH, 2)
void lstm_mfma16(const float* __restrict__ x,
                 const float* __restrict__ w_ih0, const float* __restrict__ w_hh0,
                 const float* __restrict__ b_ih0, const float* __restrict__ b_hh0,
                 const float* __restrict__ w_ih1, const float* __restrict__ w_hh1,
                 const float* __restrict__ b_ih1, const float* __restrict__ b_hh1,
                 const float* __restrict__ fc1_w, const float* __restrict__ fc1_b,
                 const float* __restrict__ fc2_w, const float* __restrict__ fc2_b,
                 float* __restrict__ out)
{
  // TWO-GROUP PHASE-OFFSET: groups A (waves 0-6) and B (waves 7-13) run
  // independent 8-batch LSTM chains. Per barrier interval, one group does its
  // MFMA phase (P1) while the other does its act phase (P2) -> matrix and
  // VALU pipes fed simultaneously by different waves (dual-issue overlap),
  // with plain block barriers as the phase clock. Each wave owns 2 M-stripes
  // (tiles 2wg, 2wg+1); per-lane 2 act items via the lay column split.
  // P1(t): MFMAs for L0(t) [U=h0(t-1)+x(t)] and L1(t-1) [same U + H=h1(t-2)].
  // P2(t): acts -> h0(t), h1(t-1). x(t+1) staged during P1(t) (loads early,
  // LDS writes after MFMAs). x8 plane prefilled in LDS. Numerics = r5 (passed).
  __shared__ __align__(16) short hbufS[2 * 4096];   // per grp: h0_0,h0_1,h1_0,h1_1 (1024 sh each)
  __shared__ __align__(16) short xstgS[2 * 2 * 128];// [grp][parity][128 sh]
  __shared__ __align__(16) float x8S[BG * T_LEN];   // [bb][t], 32 KiB
  __shared__ float sF[BG * H];
  __shared__ float sY[BG * 28];

  const int tid  = threadIdx.x;
  const int lane = tid & 63;
  const int w    = tid >> 6;
  const int c16  = lane & 15;
  const int quad = lane >> 4;

  const int  grp = (w >= 7);
  const int  wg  = grp ? (w - 7) : w;         // 0..6 within group
  const bool wgz = (wg == 0);                 // designated staging wave
  const int  lay = (lane >> 3) & 1;           // 1 -> L0 item, 0 -> L1 item
  const int  b   = lane & 7;
  const int  bg16 = grp * 8 + b;
  const int  sA = 2 * wg, sB = 2 * wg + 1;    // this wave's two M-tiles (0..13)
  const int  j4A = 4 * sA + quad, j4B = 4 * sB + quad;

  for (int i = tid; i < 4096; i += NTH) ((int*)hbufS)[i] = 0;

  // ---- weights: A[m=c16][k=quad*8+jj] per tile ----
  bfrag B0hA[2], B0lA[2], BuhA[2], BhhA[2];
  bfrag B0hB[2], B0lB[2], BuhB[2], BhhB[2];
#define LOADW(SUF, SIDX)                                                        \
  {                                                                             \
    const int np_ = 16 * (SIDX) + c16;                                          \
    const int wrow_ = (np_ & 3) * H + (np_ >> 2);                               \
    _Pragma("unroll")                                                           \
    for (int s = 0; s < 2; ++s) {                                               \
      union { short sh[8]; bfrag v; } a0h, a0l, auh, ahh;                       \
      _Pragma("unroll")                                                         \
      for (int jj = 0; jj < 8; ++jj) {                                          \
        const int k = 32 * s + quad * 8 + jj;                                   \
        const float w0 = (k < H) ? w_hh0[wrow_ * H + k]                         \
                                 : w_ih0[wrow_ * IN0 + (k - 56)];               \
        const float wu = (k < H) ? w_ih1[wrow_ * H + k] : 0.0f;                 \
        const float wh = (k < H) ? w_hh1[wrow_ * H + k] : 0.0f;                 \
        split_bf16(w0, a0h.sh[jj], a0l.sh[jj]);                                 \
        short dum;                                                              \
        split_bf16(wu, auh.sh[jj], dum);   /* RNE hi only */                    \
        split_bf16(wh, ahh.sh[jj], dum);                                        \
      }                                                                         \
      B0h##SUF[s] = a0h.v; B0l##SUF[s] = a0l.v;                                 \
      Buh##SUF[s] = auh.v; Bhh##SUF[s] = ahh.v;                                 \
    }                                                                           \
  }
  LOADW(A, sA)
  LOADW(B, sB)
#undef LOADW

  const ffrag zerof = { 0.f, 0.f, 0.f, 0.f };
#define SETUPS(SUF, J4)                                                         \
  ffrag bias0f##SUF, bias1f##SUF;                                               \
  _Pragma("unroll")                                                             \
  for (int r = 0; r < 4; ++r) {                                                 \
    const float v0 = b_ih0[r * H + (J4)] + b_hh0[r * H + (J4)];                 \
    const float v1 = b_ih1[r * H + (J4)] + b_hh1[r * H + (J4)];                 \
    bias0f##SUF[r] = (c16 < 8) ? v0 : 0.0f;                                     \
    bias1f##SUF[r] = (c16 < 8) ? v1 : 0.0f;                                     \
  }                                                                             \
  float wx8a##SUF[4];                                                           \
  _Pragma("unroll")                                                             \
  for (int r = 0; r < 4; ++r)                                                   \
    wx8a##SUF[r] = lay ? w_ih0[(r * H + (J4)) * IN0 + 8] : 0.0f;                \
  const int kk##SUF = (J4) & 31;                                                \
  const int offE##SUF = ((J4) >> 5) * 512 + ((kk##SUF >> 3) * 16 + b) * 8       \
                        + (kk##SUF & 7);
  SETUPS(A, j4A)
  SETUPS(B, j4B)
#undef SETUPS

  // h write pointers: item layer = lay. Q = t&1. L0 item -> h0 slot Q;
  // L1 item (h1(t-1)) -> h1 slot Q^1. Group base gBs = grp*4096 shorts.
  const int gBs = grp * 4096;
  short* const hwA0 = hbufS + gBs + (lay ? 0 * 1024 : 2048 + 1024) + offEA;
  short* const hwA1 = hbufS + gBs + (lay ? 1 * 1024 : 2048 + 0)    + offEA;
  short* const hwB0 = hbufS + gBs + (lay ? 0 * 1024 : 2048 + 1024) + offEB;
  short* const hwB1 = hbufS + gBs + (lay ? 1 * 1024 : 2048 + 0)    + offEB;

  // read pointers by parity P = t&1: U = h0 slot (t-1)&1 = P^1; H = h1 slot P.
  const char* const hBb = (const char*)hbufS + grp * 8192;
  const char* const xsb = (const char*)xstgS + grp * 512;
  const char* const pU0_0 = hBb + 1 * 2048 + lane * 16;
  const char* const pU0_1 = hBb + 0 * 2048 + lane * 16;
  const char* const pU1_0 = (quad == 3) ? (xsb + 0 * 256 + c16 * 16) : (pU0_0 + 1024);
  const char* const pU1_1 = (quad == 3) ? (xsb + 1 * 256 + c16 * 16) : (pU0_1 + 1024);
  const char* const pH0_0 = hBb + 4096 + 0 * 2048 + lane * 16;
  const char* const pH0_1 = hBb + 4096 + 1 * 2048 + lane * 16;

  // staging (designated wave, lanes 0-31): lane -> batch (lane>>2), elems 2e,2e+1
  const int sb_ = (lane >> 2) & 7, se_ = lane & 3;
  uint32_t* const xw_0 = (uint32_t*)((char*)xstgS + grp * 512 + 0 * 256 + sb_ * 16 + 4 * se_);
  uint32_t* const xw_1 = (uint32_t*)((char*)xstgS + grp * 512 + 1 * 256 + sb_ * 16 + 4 * se_);
  const float* xgp = x + ((size_t)(blockIdx.x * BG + grp * 8 + sb_) * T_LEN + 1) * IN0 + 2 * se_;

  // ---- prefill x8 plane; prestage x(0) into parity-0 slots ----
  for (int item = tid; item < BG * T_LEN; item += NTH) {
    const int bb = item >> 9, t = item & (T_LEN - 1);
    x8S[item] = x[((size_t)(blockIdx.x * BG + bb) * T_LEN + t) * IN0 + 8];
  }
  if (wgz && lane < 32) {
    const float* g0 = x + ((size_t)(blockIdx.x * BG + grp * 8 + sb_) * T_LEN) * IN0 + 2 * se_;
    const float xa = g0[0], xb = g0[1];
    short ah_, al_, bh_, bl_;
    split_bf16t(xa, ah_, al_); split_bf16t(xb, bh_, bl_);
    xw_0[0]  = (uint16_t)ah_ | ((uint32_t)(uint16_t)bh_ << 16);
    xw_0[32] = (uint16_t)al_ | ((uint32_t)(uint16_t)bl_ << 16);
  }

  const float* const px8 = x8S + (size_t)bg16 * T_LEN;
  float cstA = 0.f, cstB = 0.f;
  ffrag aaA, abA, ahA, aaB, abB, ahB;    // accs carried P1 -> P2 across barrier
  __syncthreads();

  // ---- phase macros ----
#define P1(P, L0P, L1P, STGF)                                                   \
  {                                                                             \
    float stga = 0.f, stgb = 0.f;                                               \
    if (STGF) { if (wgz && lane < 32) { stga = xgp[0]; stgb = xgp[1]; } }       \
    const bfrag U0 = *(const bfrag*)pU0_##P;                                    \
    const bfrag U1 = *(const bfrag*)pU1_##P;                                    \
    if (L0P) {                                                                  \
      aaA = MFMA(B0hA[0], U0, bias0fA);                                         \
      abA = MFMA(B0lA[0], U0, zerof);                                           \
      aaA = MFMA(B0hA[1], U1, aaA);                                             \
      abA = MFMA(B0lA[1], U1, abA);                                             \
      aaB = MFMA(B0hB[0], U0, bias0fB);                                         \
      abB = MFMA(B0lB[0], U0, zerof);                                           \
      aaB = MFMA(B0hB[1], U1, aaB);                                             \
      abB = MFMA(B0lB[1], U1, abB);                                             \
    }                                                                           \
    if (L1P) {                                                                  \
      const bfrag H0 = *(const bfrag*)pH0_##P;                                  \
      const bfrag H1 = *(const bfrag*)(pH0_##P + 1024);                         \
      ahA = MFMA(BhhA[0], H0, bias1fA);                                         \
      ahA = MFMA(BhhA[1], H1, ahA);                                             \
      ahA = MFMA(BuhA[0], U0, ahA);                                             \
      ahA = MFMA(BuhA[1], U1, ahA);                                             \
      ahB = MFMA(BhhB[0], H0, bias1fB);                                         \
      ahB = MFMA(BhhB[1], H1, ahB);                                             \
      ahB = MFMA(BuhB[0], U0, ahB);                                             \
      ahB = MFMA(BuhB[1], U1, ahB);                                             \
    }                                                                           \
    if (STGF) {                                                                 \
      if (wgz && lane < 32) {                                                   \
        short ah_, al_, bh_, bl_;                                               \
        split_bf16t(stga, ah_, al_); split_bf16t(stgb, bh_, bl_);               \
        uint32_t* xw = (P) ? xw_0 : xw_1;      /* stage (t+1): parity P^1 */    \
        xw[0]  = (uint16_t)ah_ | ((uint32_t)(uint16_t)bh_ << 16);               \
        xw[32] = (uint16_t)al_ | ((uint32_t)(uint16_t)bl_ << 16);               \
        xgp += IN0;                                                             \
      }                                                                         \
    }                                                                           \
  }

#define ACT1(A0A, A0B, AH, WX8, CST, HBP, X8V)                                  \
  {                                                                             \
    float sv[4];                                                                \
    _Pragma("unroll")                                                           \
    for (int r = 0; r < 4; ++r) {                                               \
      const float t0 = A0A[r] + A0B[r];                                         \
      const float uu = lay ? t0 : AH[r];                                        \
      const float vv = lay ? AH[r] : t0;                                        \
      sv[r] = uu + dpp8(vv);                                                    \
    }                                                                           \
    const float gi = fmaf(WX8[0], (X8V), sv[0]);                                \
    const float gf = fmaf(WX8[1], (X8V), sv[1]);                                \
    const float gg = fmaf(WX8[2], (X8V), sv[2]);                                \
    const float go = fmaf(WX8[3], (X8V), sv[3]);                                \
    const float iv = sigm_f(gi), fv = sigm_f(gf);                               \
    const float gv = tanh_f(gg), ov = sigm_f(go);                               \
    CST = fmaf(fv, CST, iv * gv);                                               \
    const float hv = ov * tanh_f(CST);                                          \
    short hs, hl; split_bf16t(hv, hs, hl);                                      \
    (HBP)[0] = hs; (HBP)[64] = hl;                                              \
  }

#define P2(Q, TT)                                                               \
  {                                                                             \
    const float x8v = px8[(TT)];                                                \
    ACT1(aaA, abA, ahA, wx8aA, cstA, (Q) ? hwA1 : hwA0, x8v)                    \
    ACT1(aaB, abB, ahB, wx8aB, cstB, (Q) ? hwB1 : hwB0, x8v)                    \
  }

#define P2_FIRST                                                                \
  {                                                                             \
    const float x8v = px8[0];                                                   \
    if (lay) {                                                                  \
      _Pragma("unroll")                                                         \
      for (int tt2 = 0; tt2 < 1; ++tt2) {                                       \
        float s0[4];                                                            \
        _Pragma("unroll")                                                       \
        for (int r = 0; r < 4; ++r) {                                           \
          const float t0 = aaA[r] + abA[r];                                     \
          s0[r] = t0 + dpp8(t0);                                                \
        }                                                                       \
        const float gi = fmaf(wx8aA[0], x8v, s0[0]);                            \
        const float gf = fmaf(wx8aA[1], x8v, s0[1]);                            \
        const float gg = fmaf(wx8aA[2], x8v, s0[2]);                            \
        const float go = fmaf(wx8aA[3], x8v, s0[3]);                            \
        const float iv = sigm_f(gi), fv = sigm_f(gf);                           \
        const float gv = tanh_f(gg), ov = sigm_f(go);                           \
        cstA = fmaf(fv, cstA, iv * gv);                                         \
        const float hv = ov * tanh_f(cstA);                                     \
        short hs, hl; split_bf16t(hv, hs, hl);                                  \
        hwA0[0] = hs; hwA0[64] = hl;                                            \
        float s1[4];                                                            \
        _Pragma("unroll")                                                       \
        for (int r = 0; r < 4; ++r) {                                           \
          const float t1 = aaB[r] + abB[r];                                     \
          s1[r] = t1 + dpp8(t1);                                                \
        }                                                                       \
        const float gi2 = fmaf(wx8aB[0], x8v, s1[0]);                           \
        const float gf2 = fmaf(wx8aB[1], x8v, s1[1]);                           \
        const float gg2 = fmaf(wx8aB[2], x8v, s1[2]);                           \
        const float go2 = fmaf(wx8aB[3], x8v, s1[3]);                           \
        const float iv2 = sigm_f(gi2), fv2 = sigm_f(gf2);                       \
        const float gv2 = tanh_f(gg2), ov2 = sigm_f(go2);                       \
        cstB = fmaf(fv2, cstB, iv2 * gv2);                                      \
        const float hv2 = ov2 * tanh_f(cstB);                                   \
        short hs2, hl2; split_bf16t(hv2, hs2, hl2);                             \
        hwB0[0] = hs2; hwB0[64] = hl2;                                          \
      }                                                                         \
    } else {                                                                    \
      float dmy = dpp8(aaA[0] + abA[0]) + dpp8(aaB[0] + abB[0]);                \
      asm volatile("" :: "v"(dmy));  /* keep lo-col partners live for dpp */    \
    }                                                                           \
  }

#define PFIN                                                                    \
  {                                                                             \
    float s1[4];                                                                \
    _Pragma("unroll")                                                           \
    for (int r = 0; r < 4; ++r) s1[r] = ahA[r] + dpp8(ahA[r]);                  \
    float s2[4];                                                                \
    _Pragma("unroll")                                                           \
    for (int r = 0; r < 4; ++r) s2[r] = ahB[r] + dpp8(ahB[r]);                  \
    if (lay == 0) {                                                             \
      { const float iv = sigm_f(s1[0]), fv = sigm_f(s1[1]);                     \
        const float gv = tanh_f(s1[2]), ov = sigm_f(s1[3]);                     \
        cstA = fmaf(fv, cstA, iv * gv);                                         \
        sF[bg16 * H + j4A] = ov * tanh_f(cstA); }                               \
      { const float iv = sigm_f(s2[0]), fv = sigm_f(s2[1]);                     \
        const float gv = tanh_f(s2[2]), ov = sigm_f(s2[3]);                     \
        cstB = fmaf(fv, cstB, iv * gv);                                         \
        sF[bg16 * H + j4B] = ov * tanh_f(cstB); }                               \
    }                                                                           \
  }

  // ---- peeled t=0 ----
  if (!grp) { P1(0, 1, 0, 1) }           // A: P1(0) L0-only, stage x(1)
  __syncthreads();
  if (!grp) { P2_FIRST } else { P1(0, 1, 0, 1) }
  __syncthreads();

  // ---- main: t = 1..510 in pairs ----
  int t1 = 1;
  for (int it = 0; it < 255; ++it) {
    if (!grp) { P1(1, 1, 1, 1) } else { P2(0, t1 - 1) }
    __syncthreads();
    if (!grp) { P2(1, t1) } else { P1(1, 1, 1, 1) }
    __syncthreads();
    if (!grp) { P1(0, 1, 1, 1) } else { P2(1, t1) }
    __syncthreads();
    if (!grp) { P2(0, t1 + 1) } else { P1(0, 1, 1, 1) }
    __syncthreads();
    t1 += 2;
  }
  // t1 == 511
  if (!grp) { P1(1, 1, 1, 0) } else { P2(0, t1 - 1) }
  __syncthreads();
  if (!grp) { P2(1, t1) } else { P1(1, 1, 1, 0) }
  __syncthreads();
  if (!grp) { P1(0, 0, 1, 0) } else { P2(1, t1) }   // A: L1(511) only
  __syncthreads();
  if (!grp) { PFIN } else { P1(0, 0, 1, 0) }
  __syncthreads();
  if (grp) { PFIN }
  __syncthreads();

#undef P1
#undef P2
#undef P2_FIRST
#undef PFIN
#undef ACT1

  // ---- FC head ----
  if (tid < 28 * BG) {
    const int m  = tid >> 4;
    const int bb = tid & 15;
    float acc = fc1_b[m];
    const float4* w4 = (const float4*)(fc1_w + m * H);
    const float4* h4 = (const float4*)(sF + bb * H);
    #pragma unroll
    for (int qq = 0; qq < H / 4; ++qq) {
      const float4 wv4 = w4[qq], hv4 = h4[qq];
      acc = fmaf(wv4.x, hv4.x, acc);
      acc = fmaf(wv4.y, hv4.y, acc);
      acc = fmaf(wv4.z, hv4.z, acc);
      acc = fmaf(wv4.w, hv4.w, acc);
    }
    sY[bb * 28 + m] = fmaxf(acc, 0.0f);
  }
  __syncthreads();
  if (tid < BG) {
    float acc = fc2_b[0];
    #pragma unroll
    for (int m = 0; m < 28; ++m)
      acc = fmaf(fc2_w[m], sY[tid * 28 + m], acc);
    out[blockIdx.x * BG + tid] = acc;
  }
}

extern "C" void kernel_launch(void* const* d_in, const int* in_sizes, int n_in,
                              void* d_out, int out_size, void* d_ws, size_t ws_size,
                              hipStream_t stream)
{
  const float* x     = (const float*)d_in[0];
  const float* w_ih0 = (const float*)d_in[1];
  const float* w_hh0 = (const float*)d_in[2];
  const float* b_ih0 = (const float*)d_in[3];
  const float* b_hh0 = (const float*)d_in[4];
  const float* w_ih1 = (const float*)d_in[5];
  const float* w_hh1 = (const float*)d_in[6];
  const float* b_ih1 = (const float*)d_in[7];
  const float* b_hh1 = (const float*)d_in[8];
  const float* fc1_w = (const float*)d_in[9];
  const float* fc1_b = (const float*)d_in[10];
  const float* fc2_w = (const float*)d_in[11];
  const float* fc2_b = (const float*)d_in[12];
  float* out = (float*)d_out;

  lstm_mfma16<<<NBLK, NTH, 0, stream>>>(
      x, w_ih0, w_hh0, b_ih0, b_hh0, w_ih1, w_hh1, b_ih1, b_hh1,
      fc1_w, fc1_b, fc2_w, fc2_b, out);
}

// Round 10
// 898.432 us; speedup vs baseline: 1.6114x; 1.6114x over previous
//
#include <hip/hip_runtime.h>
#include <stdint.h>

#define T_LEN 512
#define IN0   9
#define H     56
#define BG    16               // 16 batch/block: two independent 8-batch groups
#define NW    14
#define NTH   (NW * 64)        // 896 threads; waves 0-6 = group A, 7-13 = group B
#define NBLK  (2048 / BG)      // 128 blocks (idle CUs are free; wall = block chain)

typedef __attribute__((ext_vector_type(8))) short bfrag;   // 8 bf16
typedef __attribute__((ext_vector_type(4))) float ffrag;   // 4 fp32

#define MFMA(a,b,c) __builtin_amdgcn_mfma_f32_16x16x32_bf16((a),(b),(c),0,0,0)

__device__ __forceinline__ uint32_t bf16hi(float x) {
  uint32_t u = __float_as_uint(x);
  return (u + 0x7FFFu + ((u >> 16) & 1u)) & 0xFFFF0000u;
}
__device__ __forceinline__ void split_bf16(float x, short& hs, short& ls) {
  uint32_t hb = bf16hi(x);
  float lf = x - __uint_as_float(hb);
  hs = (short)(hb >> 16);
  ls = (short)(bf16hi(lf) >> 16);
}
__device__ __forceinline__ void split_bf16t(float x, short& hs, short& ls) {
  uint32_t hb = bf16hi(x);
  float lf = x - __uint_as_float(hb);
  hs = (short)(hb >> 16);
  ls = (short)(__float_as_uint(lf) >> 16);
}
__device__ __forceinline__ float dpp8(float v) {
  return __int_as_float(__builtin_amdgcn_update_dpp(0, __float_as_int(v), 0x128, 0xF, 0xF, true));
}
__device__ __forceinline__ float rcp_f(float v)  { return __builtin_amdgcn_rcpf(v); }
__device__ __forceinline__ float sigm_f(float v) { return rcp_f(1.0f + __expf(-v)); }
__device__ __forceinline__ float tanh_f(float v) { return 1.0f - 2.0f * rcp_f(1.0f + __expf(2.0f * v)); }

__global__ __launch_bounds__(NTH, 4)   // cap 128 VGPR: 14-wave block resident, no scratch
void lstm_mfma17(const float* __restrict__ x,
                 const float* __restrict__ w_ih0, const float* __restrict__ w_hh0,
                 const float* __restrict__ b_ih0, const float* __restrict__ b_hh0,
                 const float* __restrict__ w_ih1, const float* __restrict__ w_hh1,
                 const float* __restrict__ b_ih1, const float* __restrict__ b_hh1,
                 const float* __restrict__ fc1_w, const float* __restrict__ fc1_b,
                 const float* __restrict__ fc2_w, const float* __restrict__ fc2_b,
                 float* __restrict__ out)
{
  // TWO-GROUP PHASE-OFFSET (r9 protocol, correctness-verified; VGPR-budget fix).
  // Groups A (waves 0-6) / B (waves 7-13) run independent 8-batch LSTM chains.
  // Per barrier interval one group does MFMAs (P1) while the other does acts
  // (P2): matrix and VALU pipes fed simultaneously by different waves.
  // VGPR fix vs r9: launch_bounds(,4) + biases moved out of MFMA C-operands
  // (added post-reduce as per-lane scalars; -8 VGPRs, fp32 reassoc only).
  __shared__ __align__(16) short hbufS[2 * 4096];   // per grp: h0_0,h0_1,h1_0,h1_1
  __shared__ __align__(16) short xstgS[2 * 2 * 128];// [grp][parity][128 sh]
  __shared__ __align__(16) float x8S[BG * T_LEN];   // [bb][t], 32 KiB
  __shared__ float sF[BG * H];
  __shared__ float sY[BG * 28];

  const int tid  = threadIdx.x;
  const int lane = tid & 63;
  const int w    = tid >> 6;
  const int c16  = lane & 15;
  const int quad = lane >> 4;

  const int  grp = (w >= 7);
  const int  wg  = grp ? (w - 7) : w;         // 0..6 within group
  const bool wgz = (wg == 0);                 // designated staging wave
  const int  lay = (lane >> 3) & 1;           // 1 -> L0 item, 0 -> L1 item
  const int  b   = lane & 7;
  const int  bg16 = grp * 8 + b;
  const int  sA = 2 * wg, sB = 2 * wg + 1;    // this wave's two M-tiles (0..13)
  const int  j4A = 4 * sA + quad, j4B = 4 * sB + quad;

  for (int i = tid; i < 4096; i += NTH) ((int*)hbufS)[i] = 0;

  // ---- weights: A[m=c16][k=quad*8+jj] per tile ----
  bfrag B0hA[2], B0lA[2], BuhA[2], BhhA[2];
  bfrag B0hB[2], B0lB[2], BuhB[2], BhhB[2];
#define LOADW(SUF, SIDX)                                                        \
  {                                                                             \
    const int np_ = 16 * (SIDX) + c16;                                          \
    const int wrow_ = (np_ & 3) * H + (np_ >> 2);                               \
    _Pragma("unroll")                                                           \
    for (int s = 0; s < 2; ++s) {                                               \
      union { short sh[8]; bfrag v; } a0h, a0l, auh, ahh;                       \
      _Pragma("unroll")                                                         \
      for (int jj = 0; jj < 8; ++jj) {                                          \
        const int k = 32 * s + quad * 8 + jj;                                   \
        const float w0 = (k < H) ? w_hh0[wrow_ * H + k]                         \
                                 : w_ih0[wrow_ * IN0 + (k - 56)];               \
        const float wu = (k < H) ? w_ih1[wrow_ * H + k] : 0.0f;                 \
        const float wh = (k < H) ? w_hh1[wrow_ * H + k] : 0.0f;                 \
        split_bf16(w0, a0h.sh[jj], a0l.sh[jj]);                                 \
        short dum;                                                              \
        split_bf16(wu, auh.sh[jj], dum);   /* RNE hi only */                    \
        split_bf16(wh, ahh.sh[jj], dum);                                        \
      }                                                                         \
      B0h##SUF[s] = a0h.v; B0l##SUF[s] = a0l.v;                                 \
      Buh##SUF[s] = auh.v; Bhh##SUF[s] = ahh.v;                                 \
    }                                                                           \
  }
  LOADW(A, sA)
  LOADW(B, sB)
#undef LOADW

  const ffrag zerof = { 0.f, 0.f, 0.f, 0.f };
  // per-lane item bias (post-reduce add): lay=1 -> L0 biases, lay=0 -> L1.
  float bselA[4], bselB[4];
  float wx8aA[4], wx8aB[4];
  #pragma unroll
  for (int r = 0; r < 4; ++r) {
    bselA[r] = lay ? (b_ih0[r * H + j4A] + b_hh0[r * H + j4A])
                   : (b_ih1[r * H + j4A] + b_hh1[r * H + j4A]);
    bselB[r] = lay ? (b_ih0[r * H + j4B] + b_hh0[r * H + j4B])
                   : (b_ih1[r * H + j4B] + b_hh1[r * H + j4B]);
    wx8aA[r] = lay ? w_ih0[(r * H + j4A) * IN0 + 8] : 0.0f;
    wx8aB[r] = lay ? w_ih0[(r * H + j4B) * IN0 + 8] : 0.0f;
  }

  const int kkA = j4A & 31;
  const int offEA = (j4A >> 5) * 512 + ((kkA >> 3) * 16 + b) * 8 + (kkA & 7);
  const int kkB = j4B & 31;
  const int offEB = (j4B >> 5) * 512 + ((kkB >> 3) * 16 + b) * 8 + (kkB & 7);

  // h write pointers: item layer = lay. Q = t&1. L0 item -> h0 slot Q;
  // L1 item (h1(t-1)) -> h1 slot Q^1. Group base gBs = grp*4096 shorts.
  const int gBs = grp * 4096;
  short* const hwA0 = hbufS + gBs + (lay ? 0 * 1024 : 2048 + 1024) + offEA;
  short* const hwA1 = hbufS + gBs + (lay ? 1 * 1024 : 2048 + 0)    + offEA;
  short* const hwB0 = hbufS + gBs + (lay ? 0 * 1024 : 2048 + 1024) + offEB;
  short* const hwB1 = hbufS + gBs + (lay ? 1 * 1024 : 2048 + 0)    + offEB;

  // read pointers by parity P = t&1: U = h0 slot P^1; H = h1 slot P.
  const char* const hBb = (const char*)hbufS + grp * 8192;
  const char* const xsb = (const char*)xstgS + grp * 512;
  const char* const pU0_0 = hBb + 1 * 2048 + lane * 16;
  const char* const pU0_1 = hBb + 0 * 2048 + lane * 16;
  const char* const pU1_0 = (quad == 3) ? (xsb + 0 * 256 + c16 * 16) : (pU0_0 + 1024);
  const char* const pU1_1 = (quad == 3) ? (xsb + 1 * 256 + c16 * 16) : (pU0_1 + 1024);
  const char* const pH0_0 = hBb + 4096 + 0 * 2048 + lane * 16;
  const char* const pH0_1 = hBb + 4096 + 1 * 2048 + lane * 16;

  // staging (designated wave, lanes 0-31): lane -> batch (lane>>2), elems 2e,2e+1
  const int sb_ = (lane >> 2) & 7, se_ = lane & 3;
  uint32_t* const xw_0 = (uint32_t*)((char*)xstgS + grp * 512 + 0 * 256 + sb_ * 16 + 4 * se_);
  const float* xgp = x + ((size_t)(blockIdx.x * BG + grp * 8 + sb_) * T_LEN + 1) * IN0 + 2 * se_;

  // ---- prefill x8 plane; prestage x(0) into parity-0 slots ----
  for (int item = tid; item < BG * T_LEN; item += NTH) {
    const int bb = item >> 9, t = item & (T_LEN - 1);
    x8S[item] = x[((size_t)(blockIdx.x * BG + bb) * T_LEN + t) * IN0 + 8];
  }
  if (wgz && lane < 32) {
    const float* g0 = x + ((size_t)(blockIdx.x * BG + grp * 8 + sb_) * T_LEN) * IN0 + 2 * se_;
    const float xa = g0[0], xb = g0[1];
    short ah_, al_, bh_, bl_;
    split_bf16t(xa, ah_, al_); split_bf16t(xb, bh_, bl_);
    xw_0[0]  = (uint16_t)ah_ | ((uint32_t)(uint16_t)bh_ << 16);
    xw_0[32] = (uint16_t)al_ | ((uint32_t)(uint16_t)bl_ << 16);
  }

  const float* const px8 = x8S + (size_t)bg16 * T_LEN;
  float cstA = 0.f, cstB = 0.f;
  ffrag aaA, abA, ahA, aaB, abB, ahB;    // accs carried P1 -> P2 across barrier
  __syncthreads();

  // ---- phase macros ----
#define P1(P, L0P, L1P, STGF)                                                   \
  {                                                                             \
    float stga = 0.f, stgb = 0.f;                                               \
    if (STGF) { if (wgz && lane < 32) { stga = xgp[0]; stgb = xgp[1]; } }       \
    const bfrag U0 = *(const bfrag*)pU0_##P;                                    \
    const bfrag U1 = *(const bfrag*)pU1_##P;                                    \
    if (L0P) {                                                                  \
      aaA = MFMA(B0hA[0], U0, zerof);                                           \
      abA = MFMA(B0lA[0], U0, zerof);                                           \
      aaA = MFMA(B0hA[1], U1, aaA);                                             \
      abA = MFMA(B0lA[1], U1, abA);                                             \
      aaB = MFMA(B0hB[0], U0, zerof);                                           \
      abB = MFMA(B0lB[0], U0, zerof);                                           \
      aaB = MFMA(B0hB[1], U1, aaB);                                             \
      abB = MFMA(B0lB[1], U1, abB);                                             \
    }                                                                           \
    if (L1P) {                                                                  \
      const bfrag H0 = *(const bfrag*)pH0_##P;                                  \
      const bfrag H1 = *(const bfrag*)(pH0_##P + 1024);                         \
      ahA = MFMA(BhhA[0], H0, zerof);                                           \
      ahA = MFMA(BhhA[1], H1, ahA);                                             \
      ahA = MFMA(BuhA[0], U0, ahA);                                             \
      ahA = MFMA(BuhA[1], U1, ahA);                                             \
      ahB = MFMA(BhhB[0], H0, zerof);                                           \
      ahB = MFMA(BhhB[1], H1, ahB);                                             \
      ahB = MFMA(BuhB[0], U0, ahB);                                             \
      ahB = MFMA(BuhB[1], U1, ahB);                                             \
    }                                                                           \
    if (STGF) {                                                                 \
      if (wgz && lane < 32) {                                                   \
        short ah_, al_, bh_, bl_;                                               \
        split_bf16t(stga, ah_, al_); split_bf16t(stgb, bh_, bl_);               \
        uint32_t* xw = xw_0 + ((P) ? 0 : 64);  /* stage (t+1): parity P^1 */    \
        xw[0]  = (uint16_t)ah_ | ((uint32_t)(uint16_t)bh_ << 16);               \
        xw[32] = (uint16_t)al_ | ((uint32_t)(uint16_t)bl_ << 16);               \
        xgp += IN0;                                                             \
      }                                                                         \
    }                                                                           \
  }

#define ACT1(A0A, A0B, AH, WX8, BSEL, CST, HBP, X8V)                            \
  {                                                                             \
    float sv[4];                                                                \
    _Pragma("unroll")                                                           \
    for (int r = 0; r < 4; ++r) {                                               \
      const float t0 = A0A[r] + A0B[r];                                         \
      const float uu = lay ? t0 : AH[r];                                        \
      const float vv = lay ? AH[r] : t0;                                        \
      sv[r] = uu + dpp8(vv) + BSEL[r];                                          \
    }                                                                           \
    const float gi = fmaf(WX8[0], (X8V), sv[0]);                                \
    const float gf = fmaf(WX8[1], (X8V), sv[1]);                                \
    const float gg = fmaf(WX8[2], (X8V), sv[2]);                                \
    const float go = fmaf(WX8[3], (X8V), sv[3]);                                \
    const float iv = sigm_f(gi), fv = sigm_f(gf);                               \
    const float gv = tanh_f(gg), ov = sigm_f(go);                               \
    CST = fmaf(fv, CST, iv * gv);                                               \
    const float hv = ov * tanh_f(CST);                                          \
    short hs, hl; split_bf16t(hv, hs, hl);                                      \
    (HBP)[0] = hs; (HBP)[64] = hl;                                              \
  }

#define P2(Q, TT)                                                               \
  {                                                                             \
    const float x8v = px8[(TT)];                                                \
    ACT1(aaA, abA, ahA, wx8aA, bselA, cstA, (Q) ? hwA1 : hwA0, x8v)             \
    ACT1(aaB, abB, ahB, wx8aB, bselB, cstB, (Q) ? hwB1 : hwB0, x8v)             \
  }

#define P2_FIRST                                                                \
  {                                                                             \
    const float x8v = px8[0];                                                   \
    if (lay) {                                                                  \
      float s0[4];                                                              \
      _Pragma("unroll")                                                         \
      for (int r = 0; r < 4; ++r) {                                             \
        const float t0 = aaA[r] + abA[r];                                       \
        s0[r] = t0 + dpp8(t0) + bselA[r];                                       \
      }                                                                         \
      const float gi = fmaf(wx8aA[0], x8v, s0[0]);                              \
      const float gf = fmaf(wx8aA[1], x8v, s0[1]);                              \
      const float gg = fmaf(wx8aA[2], x8v, s0[2]);                              \
      const float go = fmaf(wx8aA[3], x8v, s0[3]);                              \
      const float iv = sigm_f(gi), fv = sigm_f(gf);                             \
      const float gv = tanh_f(gg), ov = sigm_f(go);                             \
      cstA = fmaf(fv, cstA, iv * gv);                                           \
      const float hv = ov * tanh_f(cstA);                                       \
      short hs, hl; split_bf16t(hv, hs, hl);                                    \
      hwA0[0] = hs; hwA0[64] = hl;                                              \
      float s1[4];                                                              \
      _Pragma("unroll")                                                         \
      for (int r = 0; r < 4; ++r) {                                             \
        const float t1 = aaB[r] + abB[r];                                       \
        s1[r] = t1 + dpp8(t1) + bselB[r];                                       \
      }                                                                         \
      const float gi2 = fmaf(wx8aB[0], x8v, s1[0]);                             \
      const float gf2 = fmaf(wx8aB[1], x8v, s1[1]);                             \
      const float gg2 = fmaf(wx8aB[2], x8v, s1[2]);                             \
      const float go2 = fmaf(wx8aB[3], x8v, s1[3]);                             \
      const float iv2 = sigm_f(gi2), fv2 = sigm_f(gf2);                         \
      const float gv2 = tanh_f(gg2), ov2 = sigm_f(go2);                         \
      cstB = fmaf(fv2, cstB, iv2 * gv2);                                        \
      const float hv2 = ov2 * tanh_f(cstB);                                     \
      short hs2, hl2; split_bf16t(hv2, hs2, hl2);                               \
      hwB0[0] = hs2; hwB0[64] = hl2;                                            \
    } else {                                                                    \
      float dmy = dpp8(aaA[0] + abA[0]) + dpp8(aaB[0] + abB[0]);                \
      asm volatile("" :: "v"(dmy));  /* keep lo-col partners live for dpp */    \
    }                                                                           \
  }

#define PFIN                                                                    \
  {                                                                             \
    float s1[4];                                                                \
    _Pragma("unroll")                                                           \
    for (int r = 0; r < 4; ++r) s1[r] = ahA[r] + dpp8(ahA[r]) + bselA[r];       \
    float s2[4];                                                                \
    _Pragma("unroll")                                                           \
    for (int r = 0; r < 4; ++r) s2[r] = ahB[r] + dpp8(ahB[r]) + bselB[r];       \
    if (lay == 0) {                                                             \
      { const float iv = sigm_f(s1[0]), fv = sigm_f(s1[1]);                     \
        const float gv = tanh_f(s1[2]), ov = sigm_f(s1[3]);                     \
        cstA = fmaf(fv, cstA, iv * gv);                                         \
        sF[bg16 * H + j4A] = ov * tanh_f(cstA); }                               \
      { const float iv = sigm_f(s2[0]), fv = sigm_f(s2[1]);                     \
        const float gv = tanh_f(s2[2]), ov = sigm_f(s2[3]);                     \
        cstB = fmaf(fv, cstB, iv * gv);                                         \
        sF[bg16 * H + j4B] = ov * tanh_f(cstB); }                               \
    }                                                                           \
  }

  // ---- peeled t=0 ----
  if (!grp) { P1(0, 1, 0, 1) }           // A: P1(0) L0-only, stage x(1)
  __syncthreads();
  if (!grp) { P2_FIRST } else { P1(0, 1, 0, 1) }
  __syncthreads();

  // ---- main: t = 1..510 in pairs ----
  int t1 = 1;
  for (int it = 0; it < 255; ++it) {
    if (!grp) { P1(1, 1, 1, 1) } else { P2(0, t1 - 1) }
    __syncthreads();
    if (!grp) { P2(1, t1) } else { P1(1, 1, 1, 1) }
    __syncthreads();
    if (!grp) { P1(0, 1, 1, 1) } else { P2(1, t1) }
    __syncthreads();
    if (!grp) { P2(0, t1 + 1) } else { P1(0, 1, 1, 1) }
    __syncthreads();
    t1 += 2;
  }
  // t1 == 511
  if (!grp) { P1(1, 1, 1, 0) } else { P2(0, t1 - 1) }
  __syncthreads();
  if (!grp) { P2(1, t1) } else { P1(1, 1, 1, 0) }
  __syncthreads();
  if (!grp) { P1(0, 0, 1, 0) } else { P2(1, t1) }   // A: L1(511) only
  __syncthreads();
  if (!grp) { PFIN } else { P1(0, 0, 1, 0) }
  __syncthreads();
  if (grp) { PFIN }
  __syncthreads();

#undef P1
#undef P2
#undef P2_FIRST
#undef PFIN
#undef ACT1

  // ---- FC head ----
  if (tid < 28 * BG) {
    const int m  = tid >> 4;
    const int bb = tid & 15;
    float acc = fc1_b[m];
    const float4* w4 = (const float4*)(fc1_w + m * H);
    const float4* h4 = (const float4*)(sF + bb * H);
    #pragma unroll
    for (int qq = 0; qq < H / 4; ++qq) {
      const float4 wv4 = w4[qq], hv4 = h4[qq];
      acc = fmaf(wv4.x, hv4.x, acc);
      acc = fmaf(wv4.y, hv4.y, acc);
      acc = fmaf(wv4.z, hv4.z, acc);
      acc = fmaf(wv4.w, hv4.w, acc);
    }
    sY[bb * 28 + m] = fmaxf(acc, 0.0f);
  }
  __syncthreads();
  if (tid < BG) {
    float acc = fc2_b[0];
    #pragma unroll
    for (int m = 0; m < 28; ++m)
      acc = fmaf(fc2_w[m], sY[tid * 28 + m], acc);
    out[blockIdx.x * BG + tid] = acc;
  }
}

extern "C" void kernel_launch(void* const* d_in, const int* in_sizes, int n_in,
                              void* d_out, int out_size, void* d_ws, size_t ws_size,
                              hipStream_t stream)
{
  const float* x     = (const float*)d_in[0];
  const float* w_ih0 = (const float*)d_in[1];
  const float* w_hh0 = (const float*)d_in[2];
  const float* b_ih0 = (const float*)d_in[3];
  const float* b_hh0 = (const float*)d_in[4];
  const float* w_ih1 = (const float*)d_in[5];
  const float* w_hh1 = (const float*)d_in[6];
  const float* b_ih1 = (const float*)d_in[7];
  const float* b_hh1 = (const float*)d_in[8];
  const float* fc1_w = (const float*)d_in[9];
  const float* fc1_b = (const float*)d_in[10];
  const float* fc2_w = (const float*)d_in[11];
  const float* fc2_b = (const float*)d_in[12];
  float* out = (float*)d_out;

  lstm_mfma17<<<NBLK, NTH, 0, stream>>>(
      x, w_ih0, w_hh0, b_ih0, b_hh0, w_ih1, w_hh1, b_ih1, b_hh1,
      fc1_w, fc1_b, fc2_w, fc2_b, out);
}